// Round 7
// baseline (460.084 us; speedup 1.0000x reference)
//
#include <hip/hip_runtime.h>

// ---------------------------------------------------------------------------
// FastLayer: AdaLN(zH,t), AdaLN(zL,t) -> concat[zHn,zLn,x] @ W_inj + b_inj
//            -> bidirectional diagonal complex SSM (S5) -> y
// B=4 L=8192 H=1024 P=64.  All inputs fp32; output fp32.
//
// Round 7: gemm8p software-pipelined reads -- ds_reads moved INTO the MFMA
// regions (one phase ahead): P0 reads t1,c0; P1 reads c1,b1 (+lgkm drain);
// P3 reads next-tile t0,b0 after vmcnt+bar. Kills the lockstep read-then-MFMA
// serialization (cycle model: MFMA 2483 + LDS 1536 summed = 48% util matches
// measured 44.7%). Staging/vmcnt/barrier discipline unchanged from the
// verified round-2 schedule. All other kernels byte-identical to round 6.
// ---------------------------------------------------------------------------

#define LN_EPS 1e-5f

typedef __attribute__((ext_vector_type(8))) short bf16x8;
typedef __attribute__((ext_vector_type(8))) unsigned short u16x8;
typedef __attribute__((ext_vector_type(4))) float f32x4;

__device__ __forceinline__ unsigned short f2bf(float f) {
  unsigned int u = __float_as_uint(f);
  u += 0x7fffu + ((u >> 16) & 1u);          // round-to-nearest-even
  return (unsigned short)(u >> 16);
}
__device__ __forceinline__ float bf2f(unsigned short s) {
  return __uint_as_float(((unsigned int)s) << 16);
}

__device__ __forceinline__ void gload16(const void* g, void* l) {
  __builtin_amdgcn_global_load_lds((const __attribute__((address_space(1))) void*)g,
                                   (__attribute__((address_space(3))) void*)l, 16, 0, 0);
}

// phase barrier: raw s_barrier, no vmcnt drain; pin compiler motion.
__device__ __forceinline__ void phase_bar() {
  __builtin_amdgcn_sched_barrier(0);
  asm volatile("" ::: "memory");
  __builtin_amdgcn_s_barrier();
  __builtin_amdgcn_sched_barrier(0);
}

// ---------------- P1 (fallback): cond projections ---------------------------
__global__ void proj_k(const float* __restrict__ t,
                       const float* __restrict__ WH, const float* __restrict__ bH,
                       const float* __restrict__ WL, const float* __restrict__ bL,
                       float* __restrict__ cond) {
  const int idx = blockIdx.x * 256 + threadIdx.x;
  const int tensor = idx >> 11;
  const int j2 = idx & 2047;
  const float* W = tensor ? WL : WH;
  const float bv = tensor ? bL[j2] : bH[j2];
  float a0 = bv, a1 = bv, a2 = bv, a3 = bv;
  #pragma unroll 4
  for (int k = 0; k < 1024; ++k) {
    const float w = W[k * 2048 + j2];
    a0 += t[k] * w; a1 += t[1024 + k] * w; a2 += t[2048 + k] * w; a3 += t[3072 + k] * w;
  }
  const int which = j2 >> 10, j = j2 & 1023;
  float* c = cond + (size_t)((tensor * 2 + which) * 4) * 1024 + j;
  c[0] = a0; c[1024] = a1; c[2048] = a2; c[3072] = a3;
}

// ---------------- merged prep kernel (FAST path) ----------------------------
__global__ void prep_k(const float* __restrict__ Winj, unsigned short* __restrict__ WinjT,
                       const float* __restrict__ Lre, const float* __restrict__ Lim,
                       const float* __restrict__ logdt,
                       const float* __restrict__ Bre, const float* __restrict__ Bim,
                       unsigned short* __restrict__ WBuT,
                       const float* __restrict__ t,
                       const float* __restrict__ WH, const float* __restrict__ WL,
                       float* __restrict__ part) {
  __shared__ float tl[64][65];
  const int bid = blockIdx.x;
  const int tid = threadIdx.x;
  if (bid < 768) {
    const int kt = bid >> 4, nt = bid & 15;
    const int k0 = kt << 6, n0 = nt << 6;
    #pragma unroll
    for (int s = 0; s < 4; ++s) {
      const int i = s * 256 + tid;
      const int r = i >> 4, c4 = i & 15;
      const float4 v = *(const float4*)&Winj[(size_t)(k0 + r) * 1024 + n0 + c4 * 4];
      tl[c4 * 4 + 0][r] = v.x; tl[c4 * 4 + 1][r] = v.y;
      tl[c4 * 4 + 2][r] = v.z; tl[c4 * 4 + 3][r] = v.w;
    }
    __syncthreads();
    const int i = tid >> 2, j0 = (tid & 3) << 4;
    u16x8 w0, w1;
    #pragma unroll
    for (int q = 0; q < 8; ++q) w0[q] = f2bf(tl[i][j0 + q]);
    #pragma unroll
    for (int q = 0; q < 8; ++q) w1[q] = f2bf(tl[i][j0 + 8 + q]);
    *(u16x8*)&WinjT[(size_t)(n0 + i) * 3072 + k0 + j0] = w0;
    *(u16x8*)&WinjT[(size_t)(n0 + i) * 3072 + k0 + j0 + 8] = w1;
  } else if (bid < 1280) {
    const int idx = (bid - 768) * 256 + tid;
    const int j = idx >> 10, hh = idx & 1023;
    const int p = j >> 1, im = j & 1;
    const float lr = Lre[p], li = Lim[p];
    const float dt = expf(logdt[p]);
    const float e = expf(lr * dt);
    float sn, cs; sincosf(li * dt, &sn, &cs);
    const float ar = e * cs - 1.f, ai = e * sn;
    const float den = lr * lr + li * li;
    const float cr = (ar * lr + ai * li) / den;
    const float ci = (ai * lr - ar * li) / den;
    const float br = Bre[p * 1024 + hh], bi = Bim[p * 1024 + hh];
    const float v = im ? (cr * bi + ci * br) : (cr * br - ci * bi);
    WBuT[idx] = f2bf(v);
  } else {
    const int pb = bid - 1280;                 // 256 blocks
    const int tensor = pb >> 7, ks = (pb >> 3) & 15, jc = pb & 7;
    const int j2 = jc * 256 + tid;
    const float* W = tensor ? WL : WH;
    float a0 = 0.f, a1 = 0.f, a2 = 0.f, a3 = 0.f;
    const int k0 = ks * 64;
    #pragma unroll 4
    for (int k = k0; k < k0 + 64; ++k) {
      const float w = W[k * 2048 + j2];
      a0 += t[k] * w; a1 += t[1024 + k] * w; a2 += t[2048 + k] * w; a3 += t[3072 + k] * w;
    }
    float* p = part + ((size_t)(tensor * 16 + ks) * 4) * 2048 + j2;
    p[0] = a0; p[2048] = a1; p[4096] = a2; p[6144] = a3;
  }
}

__global__ void proj_red_k(const float* __restrict__ part,
                           const float* __restrict__ bH, const float* __restrict__ bL,
                           float* __restrict__ cond) {
  const int idx = blockIdx.x * 256 + threadIdx.x;   // 16384
  const int tensor = idx >> 13, b = (idx >> 11) & 3, j2 = idx & 2047;
  float s = tensor ? bL[j2] : bH[j2];
  #pragma unroll
  for (int ks = 0; ks < 16; ++ks)
    s += part[((size_t)(tensor * 16 + ks) * 4 + b) * 2048 + j2];
  const int which = j2 >> 10, j = j2 & 1023;
  cond[((size_t)(tensor * 2 + which) * 4 + b) * 1024 + j] = s;
}

// ---------------- standalone prep kernels (fallback path) -------------------
__global__ void transpose_winj(const float* __restrict__ W, unsigned short* __restrict__ WT) {
  __shared__ float tl[64][65];
  const int kt = blockIdx.x >> 4, nt = blockIdx.x & 15;
  const int k0 = kt << 6, n0 = nt << 6;
  const int tid = threadIdx.x;
  #pragma unroll
  for (int s = 0; s < 4; ++s) {
    const int i = s * 256 + tid;
    const int r = i >> 4, c4 = i & 15;
    const float4 v = *(const float4*)&W[(size_t)(k0 + r) * 1024 + n0 + c4 * 4];
    tl[c4 * 4 + 0][r] = v.x; tl[c4 * 4 + 1][r] = v.y;
    tl[c4 * 4 + 2][r] = v.z; tl[c4 * 4 + 3][r] = v.w;
  }
  __syncthreads();
  const int i = tid >> 2, j0 = (tid & 3) << 4;
  u16x8 w0, w1;
  #pragma unroll
  for (int q = 0; q < 8; ++q) w0[q] = f2bf(tl[i][j0 + q]);
  #pragma unroll
  for (int q = 0; q < 8; ++q) w1[q] = f2bf(tl[i][j0 + 8 + q]);
  *(u16x8*)&WT[(size_t)(n0 + i) * 3072 + k0 + j0] = w0;
  *(u16x8*)&WT[(size_t)(n0 + i) * 3072 + k0 + j0 + 8] = w1;
}

__global__ void wbu_k(const float* __restrict__ Lre, const float* __restrict__ Lim,
                      const float* __restrict__ logdt,
                      const float* __restrict__ Bre, const float* __restrict__ Bim,
                      unsigned short* __restrict__ WBuT) {
  const int idx = blockIdx.x * 256 + threadIdx.x;
  const int j = idx >> 10, hh = idx & 1023;
  const int p = j >> 1, im = j & 1;
  const float lr = Lre[p], li = Lim[p];
  const float dt = expf(logdt[p]);
  const float e = expf(lr * dt);
  float sn, cs; sincosf(li * dt, &sn, &cs);
  const float ar = e * cs - 1.f, ai = e * sn;
  const float den = lr * lr + li * li;
  const float cr = (ar * lr + ai * li) / den;
  const float ci = (ai * lr - ar * li) / den;
  const float br = Bre[p * 1024 + hh], bi = Bim[p * 1024 + hh];
  const float v = im ? (cr * bi + ci * br) : (cr * br - ci * bi);
  WBuT[idx] = f2bf(v);
}

__global__ void w2_k(const float* __restrict__ Cfre, const float* __restrict__ Cfim,
                     const float* __restrict__ Cbre, const float* __restrict__ Cbim,
                     unsigned short* __restrict__ W2T) {
  const int idx = blockIdx.x * 256 + threadIdx.x;
  const int h = idx >> 8, k = idx & 255;
  const int p = (k & 127) >> 1, im = k & 1, bw = k >> 7;
  const float* Cre = bw ? Cbre : Cfre;
  const float* Cim = bw ? Cbim : Cfim;
  const float v = im ? (-2.f * Cim[h * 64 + p]) : (2.f * Cre[h * 64 + p]);
  W2T[idx] = f2bf(v);
}

// ---------------- P5: AdaLN -> bf16 planes (+ optional x cast) --------------
__global__ __launch_bounds__(256) void adaln_k(const float* __restrict__ zH,
                                               const float* __restrict__ zL,
                                               const float* __restrict__ x,
                                               const float* __restrict__ cond,
                                               unsigned short* __restrict__ znH,
                                               unsigned short* __restrict__ znL,
                                               unsigned short* __restrict__ xbf) {
  const int row = blockIdx.x;
  const int b = row >> 13;
  const int tid = threadIdx.x;
  const size_t rbase = (size_t)row * 1024;
  const float4 vH = *(const float4*)&zH[rbase + tid * 4];
  const float4 vL = *(const float4*)&zL[rbase + tid * 4];
  float sH = vH.x + vH.y + vH.z + vH.w;
  float qH = vH.x * vH.x + vH.y * vH.y + vH.z * vH.z + vH.w * vH.w;
  float sL = vL.x + vL.y + vL.z + vL.w;
  float qL = vL.x * vL.x + vL.y * vL.y + vL.z * vL.z + vL.w * vL.w;
  #pragma unroll
  for (int m = 1; m < 64; m <<= 1) {
    sH += __shfl_xor(sH, m); qH += __shfl_xor(qH, m);
    sL += __shfl_xor(sL, m); qL += __shfl_xor(qL, m);
  }
  __shared__ float red[4][4];
  const int wv = tid >> 6, ln = tid & 63;
  if (ln == 0) { red[wv][0] = sH; red[wv][1] = qH; red[wv][2] = sL; red[wv][3] = qL; }
  __syncthreads();
  sH = red[0][0] + red[1][0] + red[2][0] + red[3][0];
  qH = red[0][1] + red[1][1] + red[2][1] + red[3][1];
  sL = red[0][2] + red[1][2] + red[2][2] + red[3][2];
  qL = red[0][3] + red[1][3] + red[2][3] + red[3][3];
  const float muH = sH * (1.f / 1024.f);
  const float rsH = rsqrtf(qH * (1.f / 1024.f) - muH * muH + LN_EPS);
  const float muL = sL * (1.f / 1024.f);
  const float rsL = rsqrtf(qL * (1.f / 1024.f) - muL * muL + LN_EPS);
  const int h0 = tid * 4;
  const float4 scH = *(const float4*)&cond[(size_t)((0 * 2 + 0) * 4 + b) * 1024 + h0];
  const float4 shH = *(const float4*)&cond[(size_t)((0 * 2 + 1) * 4 + b) * 1024 + h0];
  const float4 scL = *(const float4*)&cond[(size_t)((1 * 2 + 0) * 4 + b) * 1024 + h0];
  const float4 shL = *(const float4*)&cond[(size_t)((1 * 2 + 1) * 4 + b) * 1024 + h0];
  ushort4 oH, oL;
  oH.x = f2bf((vH.x - muH) * rsH * (1.f + scH.x) + shH.x);
  oH.y = f2bf((vH.y - muH) * rsH * (1.f + scH.y) + shH.y);
  oH.z = f2bf((vH.z - muH) * rsH * (1.f + scH.z) + shH.z);
  oH.w = f2bf((vH.w - muH) * rsH * (1.f + scH.w) + shH.w);
  oL.x = f2bf((vL.x - muL) * rsL * (1.f + scL.x) + shL.x);
  oL.y = f2bf((vL.y - muL) * rsL * (1.f + scL.y) + shL.y);
  oL.z = f2bf((vL.z - muL) * rsL * (1.f + scL.z) + shL.z);
  oL.w = f2bf((vL.w - muL) * rsL * (1.f + scL.w) + shL.w);
  *(ushort4*)&znH[rbase + h0] = oH;
  *(ushort4*)&znL[rbase + h0] = oL;
  if (xbf != nullptr) {
    const float4 vx = *(const float4*)&x[rbase + h0];
    ushort4 ox;
    ox.x = f2bf(vx.x); ox.y = f2bf(vx.y); ox.z = f2bf(vx.z); ox.w = f2bf(vx.w);
    *(ushort4*)&xbf[rbase + h0] = ox;
  }
}

// ---------------- inj GEMM: 256x256, BK=64, 8 waves, 4-phase pipeline -------
// Round-7: ds_reads issued INSIDE the MFMA regions, one phase ahead.
//   pre-loop: read t0,b0 of tile 0 (after prologue vmcnt+bar)
//   P0: MFMA(t0xb0)  || read t1, c0           (parity tau&1 -- no in-flight writer)
//   P1: MFMA(t1xb0)  || read c1, b1 ; lgkmcnt(0)  <- all tau-reads drained
//   P2: stageA(tau+2,0); MFMA(c0xb1)              <- safe: barrier after drain
//   P3: stageA(tau+2,1); vmcnt; bar; MFMA(c1xb1) || read next t0,b0
//       (vmcnt(4) retired A(tau+1)+B(tau+1) -> post-bar reads of tau+1 safe;
//        they drain at tau+1's P1-end fence, before stage(tau+3) reuses parity)
__global__ __launch_bounds__(512, 2) void gemm8p_k(
    const unsigned short* __restrict__ znH, const unsigned short* __restrict__ znL,
    const unsigned short* __restrict__ xbf, const unsigned short* __restrict__ WinjT,
    const float* __restrict__ binj, unsigned short* __restrict__ hout) {
  __shared__ char lds[131072];
  const int tid = threadIdx.x;
  const int ln = tid & 63;
  const int w = tid >> 6;
  const int wm = w >> 2, wn = w & 3;
  const int l15 = ln & 15, l4 = ln >> 4;
  const int swz = (blockIdx.x & 7) * 64 + (blockIdx.x >> 3);   // 512 blocks, bijective
  const int r0 = (swz >> 2) << 8, n0 = (swz & 3) << 8;
  constexpr int NT = 48;

  auto stageA = [&](int tau, int hf) {
    const int pidx = tau >> 4;
    const unsigned short* plane = pidx == 0 ? znH : (pidx == 1 ? znL : xbf);
    const int kbase = (tau & 15) << 6;
    char* dst0 = lds + (tau & 1) * 65536 + hf * 16384;
    #pragma unroll
    for (int i = 0; i < 2; ++i) {
      const int idx = i * 512 + tid;
      const int rl = idx >> 3, ps = idx & 7;
      const int ls = ps ^ (rl & 7);
      const unsigned short* src = plane + (size_t)(r0 + hf * 128 + rl) * 1024 + kbase + ls * 8;
      gload16(src, dst0 + i * 8192 + ((tid & 0x1C0) << 4));
    }
  };
  auto stageB = [&](int tau, int hf) {
    char* dst0 = lds + (tau & 1) * 65536 + 32768 + hf * 16384;
    #pragma unroll
    for (int i = 0; i < 2; ++i) {
      const int idx = i * 512 + tid;
      const int rl = idx >> 3, ps = idx & 7;
      const int ls = ps ^ (rl & 7);
      const unsigned short* src = WinjT + (size_t)(n0 + hf * 128 + rl) * 3072 + tau * 64 + ls * 8;
      gload16(src, dst0 + i * 8192 + ((tid & 0x1C0) << 4));
    }
  };
  auto ldA = [&](int tau, int m, int kk) -> bf16x8 {
    const int row = wm * 128 + m * 16 + l15;
    const int ps = (kk * 4 + l4) ^ (row & 7);
    return *(const bf16x8*)(lds + (tau & 1) * 65536 + row * 128 + ps * 16);
  };
  auto ldB = [&](int tau, int n, int kk) -> bf16x8 {
    const int row = wn * 64 + n * 16 + l15;
    const int ps = (kk * 4 + l4) ^ (row & 7);
    return *(const bf16x8*)(lds + (tau & 1) * 65536 + 32768 + row * 128 + ps * 16);
  };

  f32x4 acc[8][4];
  #pragma unroll
  for (int m = 0; m < 8; ++m)
    #pragma unroll
    for (int n = 0; n < 4; ++n)
      acc[m][n] = (f32x4){0.f, 0.f, 0.f, 0.f};

  // prologue: tile0 complete + A halves of tile1; leave A(1) allowed in flight
  stageA(0, 0); stageA(0, 1); stageB(0, 0); stageB(0, 1); stageA(1, 0); stageA(1, 1);
  asm volatile("s_waitcnt vmcnt(4)" ::: "memory");
  __builtin_amdgcn_s_barrier();
  __builtin_amdgcn_sched_barrier(0);

  bf16x8 t0[4], t1[4], c0[4], c1[4], b0[4], b1[4];
  #pragma unroll
  for (int m = 0; m < 4; ++m) t0[m] = ldA(0, m, 0);
  #pragma unroll
  for (int n = 0; n < 4; ++n) b0[n] = ldB(0, n, 0);

  for (int tau = 0; tau < NT; ++tau) {
    // ---- P0: MFMA(t0 x b0) overlapped with reads of t1, c0
    if (tau + 1 < NT) stageB(tau + 1, 0);
    phase_bar();
    __builtin_amdgcn_s_setprio(1);
    #pragma unroll
    for (int m = 0; m < 4; ++m) t1[m] = ldA(tau, 4 + m, 0);
    #pragma unroll
    for (int m = 0; m < 4; ++m) c0[m] = ldA(tau, m, 1);
    #pragma unroll
    for (int m = 0; m < 4; ++m)
      #pragma unroll
      for (int n = 0; n < 4; ++n)
        acc[m][n] = __builtin_amdgcn_mfma_f32_16x16x32_bf16(t0[m], b0[n], acc[m][n], 0, 0, 0);
    __builtin_amdgcn_s_setprio(0);
    phase_bar();
    // ---- P1: MFMA(t1 x b0) overlapped with reads of c1, b1; drain all reads
    if (tau + 1 < NT) stageB(tau + 1, 1);
    phase_bar();
    __builtin_amdgcn_s_setprio(1);
    #pragma unroll
    for (int m = 0; m < 4; ++m) c1[m] = ldA(tau, 4 + m, 1);
    #pragma unroll
    for (int n = 0; n < 4; ++n) b1[n] = ldB(tau, n, 1);
    #pragma unroll
    for (int m = 0; m < 4; ++m)
      #pragma unroll
      for (int n = 0; n < 4; ++n)
        acc[4 + m][n] = __builtin_amdgcn_mfma_f32_16x16x32_bf16(t1[m], b0[n], acc[4 + m][n], 0, 0, 0);
    __builtin_amdgcn_s_setprio(0);
    asm volatile("s_waitcnt lgkmcnt(0)" ::: "memory");   // all tau-frag reads drained before A overwrite
    phase_bar();
    // ---- P2: MFMA(c0 x b1), stageA(tau+2,0)
    if (tau + 2 < NT) stageA(tau + 2, 0);
    phase_bar();
    __builtin_amdgcn_s_setprio(1);
    #pragma unroll
    for (int m = 0; m < 4; ++m)
      #pragma unroll
      for (int n = 0; n < 4; ++n)
        acc[m][n] = __builtin_amdgcn_mfma_f32_16x16x32_bf16(c0[m], b1[n], acc[m][n], 0, 0, 0);
    __builtin_amdgcn_s_setprio(0);
    phase_bar();
    // ---- P3: MFMA(c1 x b1) overlapped with next-tile t0, b0 reads
    if (tau + 2 < NT) stageA(tau + 2, 1);
    if (tau < NT - 2) { asm volatile("s_waitcnt vmcnt(4)" ::: "memory"); }
    else              { asm volatile("s_waitcnt vmcnt(0)" ::: "memory"); }
    phase_bar();
    __builtin_amdgcn_s_setprio(1);
    if (tau + 1 < NT) {
      #pragma unroll
      for (int m = 0; m < 4; ++m) t0[m] = ldA(tau + 1, m, 0);
      #pragma unroll
      for (int n = 0; n < 4; ++n) b0[n] = ldB(tau + 1, n, 0);
    }
    #pragma unroll
    for (int m = 0; m < 4; ++m)
      #pragma unroll
      for (int n = 0; n < 4; ++n)
        acc[4 + m][n] = __builtin_amdgcn_mfma_f32_16x16x32_bf16(c1[m], b1[n], acc[4 + m][n], 0, 0, 0);
    __builtin_amdgcn_s_setprio(0);
    phase_bar();
  }

  // epilogue: C/D layout col = lane&15, row = (lane>>4)*4 + reg
  #pragma unroll
  for (int n = 0; n < 4; ++n) {
    const int gcol = n0 + wn * 64 + n * 16 + l15;
    const float bv = binj[gcol];
    #pragma unroll
    for (int m = 0; m < 8; ++m) {
      const int grow = r0 + wm * 128 + m * 16 + l4 * 4;
      #pragma unroll
      for (int r = 0; r < 4; ++r)
        hout[(size_t)(grow + r) * 1024 + gcol] = f2bf(acc[m][n][r] + bv);
    }
  }
}

// ---------------- GEMM template (m97-style 128x128, BK=32, 4 waves) --------
template<int KTOT, int NTOT, int CTILES, int EPI, int AMODE>
__global__ __launch_bounds__(256, 3) void gemm_k(
    const unsigned short* __restrict__ A,
    const unsigned short* __restrict__ Bm,
    const float* __restrict__ xsrc,
    const float* __restrict__ evec,
    const unsigned short* __restrict__ hbuf,
    void* __restrict__ Cout) {
  const int tid = threadIdx.x;
  const int wv = tid >> 6, ln = tid & 63;
  const int l15 = ln & 15, l4 = ln >> 4;
  const int wr = wv >> 1, wc = wv & 1;
  const int bid = blockIdx.x;
  const int rt = bid / CTILES, ct = bid % CTILES;
  const int r0 = rt << 7, n0 = ct << 7;

  __shared__ unsigned short ldsA[128 * 32];
  __shared__ unsigned short ldsB[128 * 32];

  f32x4 acc[4][4];
  #pragma unroll
  for (int i = 0; i < 4; ++i)
    #pragma unroll
    for (int j = 0; j < 4; ++j)
      acc[i][j] = (f32x4){0.f, 0.f, 0.f, 0.f};

  for (int k0 = 0; k0 < KTOT; k0 += 32) {
    __syncthreads();
    {
      const unsigned short* bb = Bm + (size_t)n0 * KTOT + k0;
      #pragma unroll
      for (int s0 = 0; s0 < 2; ++s0) {
        const int s = wv + s0 * 4;
        const int bo = (s << 10) + (ln << 4);
        const int row = bo >> 6, inb = bo & 63;
        gload16((const char*)(bb + (size_t)row * KTOT) + inb, (char*)ldsB + (s << 10));
      }
    }
    if (AMODE == 1 && k0 >= 2048) {
      const int row = tid >> 1, kf = (tid & 1) << 4;
      const float* xp = xsrc + (size_t)(r0 + row) * 1024 + (k0 - 2048) + kf;
      const float4 v0 = *(const float4*)(xp + 0);
      const float4 v1 = *(const float4*)(xp + 4);
      const float4 v2 = *(const float4*)(xp + 8);
      const float4 v3 = *(const float4*)(xp + 12);
      u16x8 w0, w1;
      w0[0] = f2bf(v0.x); w0[1] = f2bf(v0.y); w0[2] = f2bf(v0.z); w0[3] = f2bf(v0.w);
      w0[4] = f2bf(v1.x); w0[5] = f2bf(v1.y); w0[6] = f2bf(v1.z); w0[7] = f2bf(v1.w);
      w1[0] = f2bf(v2.x); w1[1] = f2bf(v2.y); w1[2] = f2bf(v2.z); w1[3] = f2bf(v2.w);
      w1[4] = f2bf(v3.x); w1[5] = f2bf(v3.y); w1[6] = f2bf(v3.z); w1[7] = f2bf(v3.w);
      *(u16x8*)&ldsA[row * 32 + kf] = w0;
      *(u16x8*)&ldsA[row * 32 + kf + 8] = w1;
    } else {
      const unsigned short* aa;
      int astr;
      if (AMODE == 0) { aa = A + (size_t)r0 * KTOT + k0; astr = KTOT; }
      else { aa = A + (size_t)(k0 >> 10) * (32768u * 1024u) + (size_t)r0 * 1024 + (k0 & 1023); astr = 1024; }
      #pragma unroll
      for (int s0 = 0; s0 < 2; ++s0) {
        const int s = wv + s0 * 4;
        const int bo = (s << 10) + (ln << 4);
        const int row = bo >> 6, inb = bo & 63;
        gload16((const char*)(aa + (size_t)row * astr) + inb, (char*)ldsA + (s << 10));
      }
    }
    __syncthreads();
    bf16x8 af[4], bfr[4];
    #pragma unroll
    for (int i = 0; i < 4; ++i)
      af[i] = *(const bf16x8*)&ldsA[(wr * 64 + i * 16 + l15) * 32 + l4 * 8];
    #pragma unroll
    for (int j = 0; j < 4; ++j)
      bfr[j] = *(const bf16x8*)&ldsB[(wc * 64 + j * 16 + l15) * 32 + l4 * 8];
    #pragma unroll
    for (int i = 0; i < 4; ++i)
      #pragma unroll
      for (int j = 0; j < 4; ++j)
        acc[i][j] = __builtin_amdgcn_mfma_f32_16x16x32_bf16(af[i], bfr[j], acc[i][j], 0, 0, 0);
  }

  #pragma unroll
  for (int j = 0; j < 4; ++j) {
    const int gcol = n0 + wc * 64 + j * 16 + l15;
    float ev = 0.f;
    if (EPI == 1 || EPI == 3) ev = evec[gcol];
    #pragma unroll
    for (int i = 0; i < 4; ++i) {
      const int gr = r0 + wr * 64 + i * 16 + l4 * 4;
      #pragma unroll
      for (int r = 0; r < 4; ++r) {
        const size_t idx = (size_t)(gr + r) * NTOT + gcol;
        const float v = acc[i][j][r];
        if (EPI == 1)      ((unsigned short*)Cout)[idx] = f2bf(v + ev);
        else if (EPI == 2) ((float*)Cout)[idx] = v;
        else               ((float*)Cout)[idx] = v + ev * bf2f(hbuf[idx]);
      }
    }
  }
}

// ---------------- FAST: fused Bu GEMM + chunk-aggregate scans + w2 ----------
__global__ __launch_bounds__(256) void gemm_bu_k(
    const unsigned short* __restrict__ A, const unsigned short* __restrict__ Bm,
    float* __restrict__ Bu, float* __restrict__ agg,
    const float* __restrict__ Lre, const float* __restrict__ Lim,
    const float* __restrict__ logdt,
    const float* __restrict__ Cfre, const float* __restrict__ Cfim,
    const float* __restrict__ Cbre, const float* __restrict__ Cbim,
    unsigned short* __restrict__ W2T) {
  const int tid = threadIdx.x;
  if (blockIdx.x >= 256) {
    const int idx = (blockIdx.x - 256) * 256 + tid;
    const int h = idx >> 8, k = idx & 255;
    const int p = (k & 127) >> 1, im = k & 1, bw = k >> 7;
    const float* Cre = bw ? Cbre : Cfre;
    const float* Cim = bw ? Cbim : Cfim;
    const float v = im ? (-2.f * Cim[h * 64 + p]) : (2.f * Cre[h * 64 + p]);
    W2T[idx] = f2bf(v);
    return;
  }
  __shared__ unsigned short ldsA[128 * 32];
  __shared__ unsigned short ldsB[128 * 32];
  __shared__ float cbuf[128][128];
  const int wv = tid >> 6, ln = tid & 63;
  const int l15 = ln & 15, l4 = ln >> 4;
  const int wr = wv >> 1, wc = wv & 1;
  const int r0 = blockIdx.x << 7;

  f32x4 acc[4][4];
  #pragma unroll
  for (int i = 0; i < 4; ++i)
    #pragma unroll
    for (int j = 0; j < 4; ++j)
      acc[i][j] = (f32x4){0.f, 0.f, 0.f, 0.f};

  for (int k0 = 0; k0 < 1024; k0 += 32) {
    __syncthreads();
    {
      const unsigned short* bb = Bm + k0;               // n0 = 0, KTOT = 1024
      #pragma unroll
      for (int s0 = 0; s0 < 2; ++s0) {
        const int s = wv + s0 * 4;
        const int bo = (s << 10) + (ln << 4);
        const int row = bo >> 6, inb = bo & 63;
        gload16((const char*)(bb + (size_t)row * 1024) + inb, (char*)ldsB + (s << 10));
      }
    }
    {
      const unsigned short* aa = A + (size_t)r0 * 1024 + k0;
      #pragma unroll
      for (int s0 = 0; s0 < 2; ++s0) {
        const int s = wv + s0 * 4;
        const int bo = (s << 10) + (ln << 4);
        const int row = bo >> 6, inb = bo & 63;
        gload16((const char*)(aa + (size_t)row * 1024) + inb, (char*)ldsA + (s << 10));
      }
    }
    __syncthreads();
    bf16x8 af[4], bfr[4];
    #pragma unroll
    for (int i = 0; i < 4; ++i)
      af[i] = *(const bf16x8*)&ldsA[(wr * 64 + i * 16 + l15) * 32 + l4 * 8];
    #pragma unroll
    for (int j = 0; j < 4; ++j)
      bfr[j] = *(const bf16x8*)&ldsB[(wc * 64 + j * 16 + l15) * 32 + l4 * 8];
    #pragma unroll
    for (int i = 0; i < 4; ++i)
      #pragma unroll
      for (int j = 0; j < 4; ++j)
        acc[i][j] = __builtin_amdgcn_mfma_f32_16x16x32_bf16(af[i], bfr[j], acc[i][j], 0, 0, 0);
  }

  // epilogue: write C to global Bu AND LDS cbuf
  #pragma unroll
  for (int j = 0; j < 4; ++j) {
    const int lcol = wc * 64 + j * 16 + l15;
    #pragma unroll
    for (int i = 0; i < 4; ++i) {
      const int lr0 = wr * 64 + i * 16 + l4 * 4;
      #pragma unroll
      for (int r = 0; r < 4; ++r) {
        const float v = acc[i][j][r];
        Bu[(size_t)(r0 + lr0 + r) * 128 + lcol] = v;
        cbuf[lr0 + r][lcol] = v;
      }
    }
  }
  __syncthreads();
  // waves 0/1: fwd/bwd chunk-aggregate scans (64 lanes = p)
  if (wv < 2) {
    const int dir = wv, p = ln;
    const float dt = expf(logdt[p]);
    const float e = expf(Lre[p] * dt);
    float sn, cs; sincosf(Lim[p] * dt, &sn, &cs);
    const float ar = e * cs, ai = e * sn;
    float sr = 0.f, si = 0.f;
    for (int i = 0; i < 128; ++i) {
      const int off = dir ? (127 - i) : i;
      const float vr = cbuf[off][2 * p];
      const float vi = cbuf[off][2 * p + 1];
      const float nr = ar * sr - ai * si + vr;
      const float ni = ar * si + ai * sr + vi;
      sr = nr; si = ni;
    }
    const int b = r0 >> 13, ch = (r0 & 8191) >> 7;
    float* o = agg + (((size_t)dir * 4 + b) * 64 + ch) * 128 + 2 * p;
    o[0] = sr; o[1] = si;
  }
}

// ---------------- K5 (fallback): per-chunk scan aggregates ------------------
__global__ void scan_agg_k(const float* __restrict__ Bu, float* __restrict__ agg,
                           const float* __restrict__ Lre, const float* __restrict__ Lim,
                           const float* __restrict__ logdt) {
  const int bid = blockIdx.x;
  const int dir = bid >> 8, b = (bid >> 6) & 3, ch = bid & 63;
  const int p = threadIdx.x;
  const float dt = expf(logdt[p]);
  const float e = expf(Lre[p] * dt);
  float sn, cs; sincosf(Lim[p] * dt, &sn, &cs);
  const float ar = e * cs, ai = e * sn;
  const int l0 = ch << 7;
  const float* base = Bu + ((size_t)b * 8192 + l0) * 128 + 2 * p;
  float sr = 0.f, si = 0.f;
  for (int g = 0; g < 16; ++g) {
    float2 v[8];
    #pragma unroll
    for (int u = 0; u < 8; ++u) {
      const int i = g * 8 + u;
      const int off = dir ? (127 - i) : i;
      v[u] = *(const float2*)(base + (size_t)off * 128);
    }
    #pragma unroll
    for (int u = 0; u < 8; ++u) {
      const float nr = ar * sr - ai * si + v[u].x;
      const float ni = ar * si + ai * sr + v[u].y;
      sr = nr; si = ni;
    }
  }
  float* o = agg + (((size_t)dir * 4 + b) * 64 + ch) * 128 + 2 * p;
  o[0] = sr; o[1] = si;
}

// ---------------- K6 (fallback): combine chunk aggregates -------------------
__global__ void scan_comb_k(const float* __restrict__ agg, float* __restrict__ pre,
                            const float* __restrict__ Lre, const float* __restrict__ Lim,
                            const float* __restrict__ logdt) {
  const int dir = blockIdx.x >> 2, b = blockIdx.x & 3;
  const int p = threadIdx.x;
  const float dt = expf(logdt[p]);
  const float e = expf(Lre[p] * dt);
  float sn, cs; sincosf(Lim[p] * dt, &sn, &cs);
  float Ar = e * cs, Ai = e * sn;
  #pragma unroll
  for (int q = 0; q < 7; ++q) {
    const float nr = Ar * Ar - Ai * Ai; Ai = 2.f * Ar * Ai; Ar = nr;
  }
  const float* ab = agg + ((size_t)(dir * 4 + b) * 64) * 128 + 2 * p;
  float* pb = pre + ((size_t)(dir * 4 + b) * 64) * 128 + 2 * p;
  float sr = 0.f, si = 0.f;
  for (int g = 0; g < 8; ++g) {
    float2 v[8];
    #pragma unroll
    for (int u = 0; u < 8; ++u) {
      const int i = g * 8 + u;
      const int ch = dir ? (63 - i) : i;
      v[u] = *(const float2*)(ab + (size_t)ch * 128);
    }
    #pragma unroll
    for (int u = 0; u < 8; ++u) {
      const int i = g * 8 + u;
      const int ch = dir ? (63 - i) : i;
      pb[(size_t)ch * 128] = sr; pb[(size_t)ch * 128 + 1] = si;
      const float nr = Ar * sr - Ai * si + v[u].x;
      const float ni = Ar * si + Ai * sr + v[u].y;
      sr = nr; si = ni;
    }
  }
}

// ---------------- K7 (fallback): apply with precomputed prefix --------------
__global__ void scan_apply_k(const float* __restrict__ Bu, const float* __restrict__ pre,
                             unsigned short* __restrict__ Xcat,
                             const float* __restrict__ Lre, const float* __restrict__ Lim,
                             const float* __restrict__ logdt) {
  const int bid = blockIdx.x;
  const int dir = bid >> 8, b = (bid >> 6) & 3, ch = bid & 63;
  const int p = threadIdx.x;
  const float dt = expf(logdt[p]);
  const float e = expf(Lre[p] * dt);
  float sn, cs; sincosf(Lim[p] * dt, &sn, &cs);
  const float ar = e * cs, ai = e * sn;
  const int l0 = ch << 7;
  const float* base = Bu + ((size_t)b * 8192 + l0) * 128 + 2 * p;
  const float* pr = pre + (((size_t)dir * 4 + b) * 64 + ch) * 128 + 2 * p;
  float sr = pr[0], si = pr[1];
  unsigned short* xb = Xcat + ((size_t)b * 8192 + l0) * 256 + dir * 128 + 2 * p;
  for (int g = 0; g < 16; ++g) {
    float2 v[8];
    #pragma unroll
    for (int u = 0; u < 8; ++u) {
      const int i = g * 8 + u;
      const int off = dir ? (127 - i) : i;
      v[u] = *(const float2*)(base + (size_t)off * 128);
    }
    #pragma unroll
    for (int u = 0; u < 8; ++u) {
      const int i = g * 8 + u;
      const int off = dir ? (127 - i) : i;
      const float nr = ar * sr - ai * si + v[u].x;
      const float ni = ar * si + ai * sr + v[u].y;
      sr = nr; si = ni;
      ushort2 ov; ov.x = f2bf(sr); ov.y = f2bf(si);
      *(ushort2*)(xb + (size_t)off * 256) = ov;
    }
  }
}

// ---------------- K7' (FAST): apply with inline prefix from agg -------------
__global__ void scan_apply2_k(const float* __restrict__ Bu, const float* __restrict__ agg,
                              unsigned short* __restrict__ Xcat,
                              const float* __restrict__ Lre, const float* __restrict__ Lim,
                              const float* __restrict__ logdt) {
  const int bid = blockIdx.x;
  const int dir = bid >> 8, b = (bid >> 6) & 3, ch = bid & 63;
  const int p = threadIdx.x;
  const float dt = expf(logdt[p]);
  const float e = expf(Lre[p] * dt);
  float sn, cs; sincosf(Lim[p] * dt, &sn, &cs);
  const float ar = e * cs, ai = e * sn;
  float Ar = ar, Ai = ai;
  #pragma unroll
  for (int q = 0; q < 7; ++q) {              // A^128
    const float nr = Ar * Ar - Ai * Ai; Ai = 2.f * Ar * Ai; Ar = nr;
  }
  const float* ab = agg + ((size_t)(dir * 4 + b) * 64) * 128 + 2 * p;
  float sr = 0.f, si = 0.f;
  const int nk = dir ? (63 - ch) : ch;       // # preceding chunks in scan order
  for (int g0 = 0; g0 < nk; g0 += 8) {
    const int gn = (nk - g0) < 8 ? (nk - g0) : 8;
    float2 v[8];
    for (int u = 0; u < gn; ++u) {
      const int i = g0 + u;
      const int k = dir ? (63 - i) : i;
      v[u] = *(const float2*)(ab + (size_t)k * 128);
    }
    for (int u = 0; u < gn; ++u) {
      const float nr = Ar * sr - Ai * si + v[u].x;
      const float ni = Ar * si + Ai * sr + v[u].y;
      sr = nr; si = ni;
    }
  }
  const int l0 = ch << 7;
  const float* base = Bu + ((size_t)b * 8192 + l0) * 128 + 2 * p;
  unsigned short* xb = Xcat + ((size_t)b * 8192 + l0) * 256 + dir * 128 + 2 * p;
  for (int g = 0; g < 16; ++g) {
    float2 v[8];
    #pragma unroll
    for (int u = 0; u < 8; ++u) {
      const int i = g * 8 + u;
      const int off = dir ? (127 - i) : i;
      v[u] = *(const float2*)(base + (size_t)off * 128);
    }
    #pragma unroll
    for (int u = 0; u < 8; ++u) {
      const int i = g * 8 + u;
      const int off = dir ? (127 - i) : i;
      const float nr = ar * sr - ai * si + v[u].x;
      const float ni = ar * si + ai * sr + v[u].y;
      sr = nr; si = ni;
      ushort2 ov; ov.x = f2bf(sr); ov.y = f2bf(si);
      *(ushort2*)(xb + (size_t)off * 256) = ov;
    }
  }
}

// ---------------------------------------------------------------------------
extern "C" void kernel_launch(void* const* d_in, const int* in_sizes, int n_in,
                              void* d_out, int out_size, void* d_ws, size_t ws_size,
                              hipStream_t stream) {
  const float* zH    = (const float*)d_in[0];
  const float* zL    = (const float*)d_in[1];
  const float* x     = (const float*)d_in[2];
  const float* t     = (const float*)d_in[3];
  const float* WpH   = (const float*)d_in[4];
  const float* bpH   = (const float*)d_in[5];
  const float* WpL   = (const float*)d_in[6];
  const float* bpL   = (const float*)d_in[7];
  const float* Winj  = (const float*)d_in[8];
  const float* binj  = (const float*)d_in[9];
  const float* Lre   = (const float*)d_in[10];
  const float* Lim   = (const float*)d_in[11];
  const float* Bre   = (const float*)d_in[12];
  const float* Bim   = (const float*)d_in[13];
  const float* Cfre  = (const float*)d_in[14];
  const float* Cfim  = (const float*)d_in[15];
  const float* Cbre  = (const float*)d_in[16];
  const float* Cbim  = (const float*)d_in[17];
  const float* Dv    = (const float*)d_in[18];
  const float* logdt = (const float*)d_in[19];

  unsigned short* znH = (unsigned short*)d_out;          // d_out as scratch until K8
  unsigned short* znL = znH + (size_t)32768 * 1024;

  const bool FAST = ws_size >= 141950976ull;
  char* ws = (char*)d_ws;

  if (FAST) {
    unsigned short* WinjT = (unsigned short*)(ws + 0);
    unsigned short* hbuf  = (unsigned short*)(ws + 6291456);
    unsigned short* WBuT  = (unsigned short*)(ws + 73400320);
    float*          cond  = (float*)(ws + 73662464);
    float*          part  = (float*)(ws + 73793536);
    char*           U     = ws + 74842112;               // union region
    unsigned short* xbf   = (unsigned short*)U;          // 64 MB, dead after inj GEMM
    float*          Bu    = (float*)(U + 0);             // 16 MB (after gemm8p)
    float*          agg   = (float*)(U + 16777216);      // 256 KB
    unsigned short* Xcat  = (unsigned short*)(U + 17301504);  // 16 MB
    unsigned short* W2T   = (unsigned short*)(U + 34078720);  // 0.5 MB (after gemm8p)

    prep_k<<<1536, 256, 0, stream>>>(Winj, WinjT, Lre, Lim, logdt, Bre, Bim, WBuT,
                                     t, WpH, WpL, part);
    proj_red_k<<<64, 256, 0, stream>>>(part, bpH, bpL, cond);
    adaln_k<<<32768, 256, 0, stream>>>(zH, zL, x, cond, znH, znL, xbf);
    gemm8p_k<<<512, 512, 0, stream>>>(znH, znL, xbf, WinjT, binj, hbuf);
    gemm_bu_k<<<1280, 256, 0, stream>>>(hbuf, WBuT, Bu, agg, Lre, Lim, logdt,
                                        Cfre, Cfim, Cbre, Cbim, W2T);
    scan_apply2_k<<<512, 64, 0, stream>>>(Bu, agg, Xcat, Lre, Lim, logdt);
    gemm_k<256, 1024, 8, 3, 0><<<2048, 256, 0, stream>>>(Xcat, W2T, nullptr, Dv, hbuf, (float*)d_out);
  } else {
    // round-1 fallback (ws >= 108.4 MB proven)
    unsigned short* WinjT = (unsigned short*)ws; ws += (size_t)1024 * 3072 * 2;
    unsigned short* hbuf  = (unsigned short*)ws; ws += (size_t)32768 * 1024 * 2;
    unsigned short* WBuT  = (unsigned short*)ws; ws += (size_t)128 * 1024 * 2;
    float*          Bu    = (float*)ws;          ws += (size_t)32768 * 128 * 4;
    float*          cond  = (float*)ws;          ws += (size_t)2 * 2 * 4 * 1024 * 4;
    float*          agg   = (float*)ws;          ws += (size_t)2 * 4 * 64 * 128 * 4;
    float*          pre   = (float*)ws;          ws += (size_t)2 * 4 * 64 * 128 * 4;
    unsigned short* Xcat  = (unsigned short*)ws; ws += (size_t)32768 * 256 * 2;
    unsigned short* W2T   = (unsigned short*)ws; ws += (size_t)1024 * 256 * 2;

    proj_k<<<16, 256, 0, stream>>>(t, WpH, bpH, WpL, bpL, cond);
    transpose_winj<<<768, 256, 0, stream>>>(Winj, WinjT);
    wbu_k<<<512, 256, 0, stream>>>(Lre, Lim, logdt, Bre, Bim, WBuT);
    w2_k<<<1024, 256, 0, stream>>>(Cfre, Cfim, Cbre, Cbim, W2T);
    adaln_k<<<32768, 256, 0, stream>>>(zH, zL, x, cond, znH, znL, nullptr);
    gemm_k<3072, 1024, 8, 1, 1><<<2048, 256, 0, stream>>>(znH, WinjT, x, binj, nullptr, hbuf);
    gemm_k<1024, 128, 1, 2, 0><<<256, 256, 0, stream>>>(hbuf, WBuT, nullptr, nullptr, nullptr, Bu);
    scan_agg_k<<<512, 64, 0, stream>>>(Bu, agg, Lre, Lim, logdt);
    scan_comb_k<<<8, 64, 0, stream>>>(agg, pre, Lre, Lim, logdt);
    scan_apply_k<<<512, 64, 0, stream>>>(Bu, pre, Xcat, Lre, Lim, logdt);
    gemm_k<256, 1024, 8, 3, 0><<<2048, 256, 0, stream>>>(Xcat, W2T, nullptr, Dv, hbuf, (float*)d_out);
  }
}

// Round 8
// 402.638 us; speedup vs baseline: 1.1427x; 1.1427x over previous
//
#include <hip/hip_runtime.h>

// ---------------------------------------------------------------------------
// FastLayer: AdaLN(zH,t), AdaLN(zL,t) -> concat[zHn,zLn,x] @ W_inj + b_inj
//            -> bidirectional diagonal complex SSM (S5) -> y
// B=4 L=8192 H=1024 P=64.  All inputs fp32; output fp32.
//
// Round 8 vs round 7:
//  (1) GEMM epilogues: store loops reordered row-outer/colgroup-inner so the
//      4 adjacent 32B(bf16)/64B(fp32) segments of one row are issued
//      back-to-back (L2 write-combining; gemm8p WRITE_SIZE was 2x the data).
//  (2) gemm_bu: double-buffered K-loop with vmcnt(4) (was full-drain at
//      1 block/CU -> latency-serialized).
//  (3) FAST scan path reverted to scan_comb_k + scan_apply_k (r2 structure;
//      inline-prefix version did redundant serial MACs).
// gemm8p K-loop unchanged from round 7 (199us best measured).
// ---------------------------------------------------------------------------

#define LN_EPS 1e-5f

typedef __attribute__((ext_vector_type(8))) short bf16x8;
typedef __attribute__((ext_vector_type(8))) unsigned short u16x8;
typedef __attribute__((ext_vector_type(4))) float f32x4;

__device__ __forceinline__ unsigned short f2bf(float f) {
  unsigned int u = __float_as_uint(f);
  u += 0x7fffu + ((u >> 16) & 1u);          // round-to-nearest-even
  return (unsigned short)(u >> 16);
}
__device__ __forceinline__ float bf2f(unsigned short s) {
  return __uint_as_float(((unsigned int)s) << 16);
}

__device__ __forceinline__ void gload16(const void* g, void* l) {
  __builtin_amdgcn_global_load_lds((const __attribute__((address_space(1))) void*)g,
                                   (__attribute__((address_space(3))) void*)l, 16, 0, 0);
}

// phase barrier: raw s_barrier, no vmcnt drain; pin compiler motion.
__device__ __forceinline__ void phase_bar() {
  __builtin_amdgcn_sched_barrier(0);
  asm volatile("" ::: "memory");
  __builtin_amdgcn_s_barrier();
  __builtin_amdgcn_sched_barrier(0);
}

// ---------------- P1 (fallback): cond projections ---------------------------
__global__ void proj_k(const float* __restrict__ t,
                       const float* __restrict__ WH, const float* __restrict__ bH,
                       const float* __restrict__ WL, const float* __restrict__ bL,
                       float* __restrict__ cond) {
  const int idx = blockIdx.x * 256 + threadIdx.x;
  const int tensor = idx >> 11;
  const int j2 = idx & 2047;
  const float* W = tensor ? WL : WH;
  const float bv = tensor ? bL[j2] : bH[j2];
  float a0 = bv, a1 = bv, a2 = bv, a3 = bv;
  #pragma unroll 4
  for (int k = 0; k < 1024; ++k) {
    const float w = W[k * 2048 + j2];
    a0 += t[k] * w; a1 += t[1024 + k] * w; a2 += t[2048 + k] * w; a3 += t[3072 + k] * w;
  }
  const int which = j2 >> 10, j = j2 & 1023;
  float* c = cond + (size_t)((tensor * 2 + which) * 4) * 1024 + j;
  c[0] = a0; c[1024] = a1; c[2048] = a2; c[3072] = a3;
}

// ---------------- merged prep kernel (FAST path) ----------------------------
__global__ void prep_k(const float* __restrict__ Winj, unsigned short* __restrict__ WinjT,
                       const float* __restrict__ Lre, const float* __restrict__ Lim,
                       const float* __restrict__ logdt,
                       const float* __restrict__ Bre, const float* __restrict__ Bim,
                       unsigned short* __restrict__ WBuT,
                       const float* __restrict__ t,
                       const float* __restrict__ WH, const float* __restrict__ WL,
                       float* __restrict__ part) {
  __shared__ float tl[64][65];
  const int bid = blockIdx.x;
  const int tid = threadIdx.x;
  if (bid < 768) {
    const int kt = bid >> 4, nt = bid & 15;
    const int k0 = kt << 6, n0 = nt << 6;
    #pragma unroll
    for (int s = 0; s < 4; ++s) {
      const int i = s * 256 + tid;
      const int r = i >> 4, c4 = i & 15;
      const float4 v = *(const float4*)&Winj[(size_t)(k0 + r) * 1024 + n0 + c4 * 4];
      tl[c4 * 4 + 0][r] = v.x; tl[c4 * 4 + 1][r] = v.y;
      tl[c4 * 4 + 2][r] = v.z; tl[c4 * 4 + 3][r] = v.w;
    }
    __syncthreads();
    const int i = tid >> 2, j0 = (tid & 3) << 4;
    u16x8 w0, w1;
    #pragma unroll
    for (int q = 0; q < 8; ++q) w0[q] = f2bf(tl[i][j0 + q]);
    #pragma unroll
    for (int q = 0; q < 8; ++q) w1[q] = f2bf(tl[i][j0 + 8 + q]);
    *(u16x8*)&WinjT[(size_t)(n0 + i) * 3072 + k0 + j0] = w0;
    *(u16x8*)&WinjT[(size_t)(n0 + i) * 3072 + k0 + j0 + 8] = w1;
  } else if (bid < 1280) {
    const int idx = (bid - 768) * 256 + tid;
    const int j = idx >> 10, hh = idx & 1023;
    const int p = j >> 1, im = j & 1;
    const float lr = Lre[p], li = Lim[p];
    const float dt = expf(logdt[p]);
    const float e = expf(lr * dt);
    float sn, cs; sincosf(li * dt, &sn, &cs);
    const float ar = e * cs - 1.f, ai = e * sn;
    const float den = lr * lr + li * li;
    const float cr = (ar * lr + ai * li) / den;
    const float ci = (ai * lr - ar * li) / den;
    const float br = Bre[p * 1024 + hh], bi = Bim[p * 1024 + hh];
    const float v = im ? (cr * bi + ci * br) : (cr * br - ci * bi);
    WBuT[idx] = f2bf(v);
  } else {
    const int pb = bid - 1280;                 // 256 blocks
    const int tensor = pb >> 7, ks = (pb >> 3) & 15, jc = pb & 7;
    const int j2 = jc * 256 + tid;
    const float* W = tensor ? WL : WH;
    float a0 = 0.f, a1 = 0.f, a2 = 0.f, a3 = 0.f;
    const int k0 = ks * 64;
    #pragma unroll 4
    for (int k = k0; k < k0 + 64; ++k) {
      const float w = W[k * 2048 + j2];
      a0 += t[k] * w; a1 += t[1024 + k] * w; a2 += t[2048 + k] * w; a3 += t[3072 + k] * w;
    }
    float* p = part + ((size_t)(tensor * 16 + ks) * 4) * 2048 + j2;
    p[0] = a0; p[2048] = a1; p[4096] = a2; p[6144] = a3;
  }
}

__global__ void proj_red_k(const float* __restrict__ part,
                           const float* __restrict__ bH, const float* __restrict__ bL,
                           float* __restrict__ cond) {
  const int idx = blockIdx.x * 256 + threadIdx.x;   // 16384
  const int tensor = idx >> 13, b = (idx >> 11) & 3, j2 = idx & 2047;
  float s = tensor ? bL[j2] : bH[j2];
  #pragma unroll
  for (int ks = 0; ks < 16; ++ks)
    s += part[((size_t)(tensor * 16 + ks) * 4 + b) * 2048 + j2];
  const int which = j2 >> 10, j = j2 & 1023;
  cond[((size_t)(tensor * 2 + which) * 4 + b) * 1024 + j] = s;
}

// ---------------- standalone prep kernels (fallback path) -------------------
__global__ void transpose_winj(const float* __restrict__ W, unsigned short* __restrict__ WT) {
  __shared__ float tl[64][65];
  const int kt = blockIdx.x >> 4, nt = blockIdx.x & 15;
  const int k0 = kt << 6, n0 = nt << 6;
  const int tid = threadIdx.x;
  #pragma unroll
  for (int s = 0; s < 4; ++s) {
    const int i = s * 256 + tid;
    const int r = i >> 4, c4 = i & 15;
    const float4 v = *(const float4*)&W[(size_t)(k0 + r) * 1024 + n0 + c4 * 4];
    tl[c4 * 4 + 0][r] = v.x; tl[c4 * 4 + 1][r] = v.y;
    tl[c4 * 4 + 2][r] = v.z; tl[c4 * 4 + 3][r] = v.w;
  }
  __syncthreads();
  const int i = tid >> 2, j0 = (tid & 3) << 4;
  u16x8 w0, w1;
  #pragma unroll
  for (int q = 0; q < 8; ++q) w0[q] = f2bf(tl[i][j0 + q]);
  #pragma unroll
  for (int q = 0; q < 8; ++q) w1[q] = f2bf(tl[i][j0 + 8 + q]);
  *(u16x8*)&WT[(size_t)(n0 + i) * 3072 + k0 + j0] = w0;
  *(u16x8*)&WT[(size_t)(n0 + i) * 3072 + k0 + j0 + 8] = w1;
}

__global__ void wbu_k(const float* __restrict__ Lre, const float* __restrict__ Lim,
                      const float* __restrict__ logdt,
                      const float* __restrict__ Bre, const float* __restrict__ Bim,
                      unsigned short* __restrict__ WBuT) {
  const int idx = blockIdx.x * 256 + threadIdx.x;
  const int j = idx >> 10, hh = idx & 1023;
  const int p = j >> 1, im = j & 1;
  const float lr = Lre[p], li = Lim[p];
  const float dt = expf(logdt[p]);
  const float e = expf(lr * dt);
  float sn, cs; sincosf(li * dt, &sn, &cs);
  const float ar = e * cs - 1.f, ai = e * sn;
  const float den = lr * lr + li * li;
  const float cr = (ar * lr + ai * li) / den;
  const float ci = (ai * lr - ar * li) / den;
  const float br = Bre[p * 1024 + hh], bi = Bim[p * 1024 + hh];
  const float v = im ? (cr * bi + ci * br) : (cr * br - ci * bi);
  WBuT[idx] = f2bf(v);
}

__global__ void w2_k(const float* __restrict__ Cfre, const float* __restrict__ Cfim,
                     const float* __restrict__ Cbre, const float* __restrict__ Cbim,
                     unsigned short* __restrict__ W2T) {
  const int idx = blockIdx.x * 256 + threadIdx.x;
  const int h = idx >> 8, k = idx & 255;
  const int p = (k & 127) >> 1, im = k & 1, bw = k >> 7;
  const float* Cre = bw ? Cbre : Cfre;
  const float* Cim = bw ? Cbim : Cfim;
  const float v = im ? (-2.f * Cim[h * 64 + p]) : (2.f * Cre[h * 64 + p]);
  W2T[idx] = f2bf(v);
}

// ---------------- P5: AdaLN -> bf16 planes (+ optional x cast) --------------
__global__ __launch_bounds__(256) void adaln_k(const float* __restrict__ zH,
                                               const float* __restrict__ zL,
                                               const float* __restrict__ x,
                                               const float* __restrict__ cond,
                                               unsigned short* __restrict__ znH,
                                               unsigned short* __restrict__ znL,
                                               unsigned short* __restrict__ xbf) {
  const int row = blockIdx.x;
  const int b = row >> 13;
  const int tid = threadIdx.x;
  const size_t rbase = (size_t)row * 1024;
  const float4 vH = *(const float4*)&zH[rbase + tid * 4];
  const float4 vL = *(const float4*)&zL[rbase + tid * 4];
  float sH = vH.x + vH.y + vH.z + vH.w;
  float qH = vH.x * vH.x + vH.y * vH.y + vH.z * vH.z + vH.w * vH.w;
  float sL = vL.x + vL.y + vL.z + vL.w;
  float qL = vL.x * vL.x + vL.y * vL.y + vL.z * vL.z + vL.w * vL.w;
  #pragma unroll
  for (int m = 1; m < 64; m <<= 1) {
    sH += __shfl_xor(sH, m); qH += __shfl_xor(qH, m);
    sL += __shfl_xor(sL, m); qL += __shfl_xor(qL, m);
  }
  __shared__ float red[4][4];
  const int wv = tid >> 6, ln = tid & 63;
  if (ln == 0) { red[wv][0] = sH; red[wv][1] = qH; red[wv][2] = sL; red[wv][3] = qL; }
  __syncthreads();
  sH = red[0][0] + red[1][0] + red[2][0] + red[3][0];
  qH = red[0][1] + red[1][1] + red[2][1] + red[3][1];
  sL = red[0][2] + red[1][2] + red[2][2] + red[3][2];
  qL = red[0][3] + red[1][3] + red[2][3] + red[3][3];
  const float muH = sH * (1.f / 1024.f);
  const float rsH = rsqrtf(qH * (1.f / 1024.f) - muH * muH + LN_EPS);
  const float muL = sL * (1.f / 1024.f);
  const float rsL = rsqrtf(qL * (1.f / 1024.f) - muL * muL + LN_EPS);
  const int h0 = tid * 4;
  const float4 scH = *(const float4*)&cond[(size_t)((0 * 2 + 0) * 4 + b) * 1024 + h0];
  const float4 shH = *(const float4*)&cond[(size_t)((0 * 2 + 1) * 4 + b) * 1024 + h0];
  const float4 scL = *(const float4*)&cond[(size_t)((1 * 2 + 0) * 4 + b) * 1024 + h0];
  const float4 shL = *(const float4*)&cond[(size_t)((1 * 2 + 1) * 4 + b) * 1024 + h0];
  ushort4 oH, oL;
  oH.x = f2bf((vH.x - muH) * rsH * (1.f + scH.x) + shH.x);
  oH.y = f2bf((vH.y - muH) * rsH * (1.f + scH.y) + shH.y);
  oH.z = f2bf((vH.z - muH) * rsH * (1.f + scH.z) + shH.z);
  oH.w = f2bf((vH.w - muH) * rsH * (1.f + scH.w) + shH.w);
  oL.x = f2bf((vL.x - muL) * rsL * (1.f + scL.x) + shL.x);
  oL.y = f2bf((vL.y - muL) * rsL * (1.f + scL.y) + shL.y);
  oL.z = f2bf((vL.z - muL) * rsL * (1.f + scL.z) + shL.z);
  oL.w = f2bf((vL.w - muL) * rsL * (1.f + scL.w) + shL.w);
  *(ushort4*)&znH[rbase + h0] = oH;
  *(ushort4*)&znL[rbase + h0] = oL;
  if (xbf != nullptr) {
    const float4 vx = *(const float4*)&x[rbase + h0];
    ushort4 ox;
    ox.x = f2bf(vx.x); ox.y = f2bf(vx.y); ox.z = f2bf(vx.z); ox.w = f2bf(vx.w);
    *(ushort4*)&xbf[rbase + h0] = ox;
  }
}

// ---------------- inj GEMM: 256x256, BK=64, 8 waves, 4-phase pipeline -------
// K-loop identical to round 7 (best measured). Epilogue store order changed:
// row outer, col-group inner -> 4 adjacent 32B bursts per row (write-combine).
__global__ __launch_bounds__(512, 2) void gemm8p_k(
    const unsigned short* __restrict__ znH, const unsigned short* __restrict__ znL,
    const unsigned short* __restrict__ xbf, const unsigned short* __restrict__ WinjT,
    const float* __restrict__ binj, unsigned short* __restrict__ hout) {
  __shared__ char lds[131072];
  const int tid = threadIdx.x;
  const int ln = tid & 63;
  const int w = tid >> 6;
  const int wm = w >> 2, wn = w & 3;
  const int l15 = ln & 15, l4 = ln >> 4;
  const int swz = (blockIdx.x & 7) * 64 + (blockIdx.x >> 3);   // 512 blocks, bijective
  const int r0 = (swz >> 2) << 8, n0 = (swz & 3) << 8;
  constexpr int NT = 48;

  auto stageA = [&](int tau, int hf) {
    const int pidx = tau >> 4;
    const unsigned short* plane = pidx == 0 ? znH : (pidx == 1 ? znL : xbf);
    const int kbase = (tau & 15) << 6;
    char* dst0 = lds + (tau & 1) * 65536 + hf * 16384;
    #pragma unroll
    for (int i = 0; i < 2; ++i) {
      const int idx = i * 512 + tid;
      const int rl = idx >> 3, ps = idx & 7;
      const int ls = ps ^ (rl & 7);
      const unsigned short* src = plane + (size_t)(r0 + hf * 128 + rl) * 1024 + kbase + ls * 8;
      gload16(src, dst0 + i * 8192 + ((tid & 0x1C0) << 4));
    }
  };
  auto stageB = [&](int tau, int hf) {
    char* dst0 = lds + (tau & 1) * 65536 + 32768 + hf * 16384;
    #pragma unroll
    for (int i = 0; i < 2; ++i) {
      const int idx = i * 512 + tid;
      const int rl = idx >> 3, ps = idx & 7;
      const int ls = ps ^ (rl & 7);
      const unsigned short* src = WinjT + (size_t)(n0 + hf * 128 + rl) * 3072 + tau * 64 + ls * 8;
      gload16(src, dst0 + i * 8192 + ((tid & 0x1C0) << 4));
    }
  };
  auto ldA = [&](int tau, int m, int kk) -> bf16x8 {
    const int row = wm * 128 + m * 16 + l15;
    const int ps = (kk * 4 + l4) ^ (row & 7);
    return *(const bf16x8*)(lds + (tau & 1) * 65536 + row * 128 + ps * 16);
  };
  auto ldB = [&](int tau, int n, int kk) -> bf16x8 {
    const int row = wn * 64 + n * 16 + l15;
    const int ps = (kk * 4 + l4) ^ (row & 7);
    return *(const bf16x8*)(lds + (tau & 1) * 65536 + 32768 + row * 128 + ps * 16);
  };

  f32x4 acc[8][4];
  #pragma unroll
  for (int m = 0; m < 8; ++m)
    #pragma unroll
    for (int n = 0; n < 4; ++n)
      acc[m][n] = (f32x4){0.f, 0.f, 0.f, 0.f};

  // prologue: tile0 complete + A halves of tile1; leave A(1) allowed in flight
  stageA(0, 0); stageA(0, 1); stageB(0, 0); stageB(0, 1); stageA(1, 0); stageA(1, 1);
  asm volatile("s_waitcnt vmcnt(4)" ::: "memory");
  __builtin_amdgcn_s_barrier();
  __builtin_amdgcn_sched_barrier(0);

  bf16x8 t0[4], t1[4], c0[4], c1[4], b0[4], b1[4];
  #pragma unroll
  for (int m = 0; m < 4; ++m) t0[m] = ldA(0, m, 0);
  #pragma unroll
  for (int n = 0; n < 4; ++n) b0[n] = ldB(0, n, 0);

  for (int tau = 0; tau < NT; ++tau) {
    // ---- P0: MFMA(t0 x b0) overlapped with reads of t1, c0
    if (tau + 1 < NT) stageB(tau + 1, 0);
    phase_bar();
    __builtin_amdgcn_s_setprio(1);
    #pragma unroll
    for (int m = 0; m < 4; ++m) t1[m] = ldA(tau, 4 + m, 0);
    #pragma unroll
    for (int m = 0; m < 4; ++m) c0[m] = ldA(tau, m, 1);
    #pragma unroll
    for (int m = 0; m < 4; ++m)
      #pragma unroll
      for (int n = 0; n < 4; ++n)
        acc[m][n] = __builtin_amdgcn_mfma_f32_16x16x32_bf16(t0[m], b0[n], acc[m][n], 0, 0, 0);
    __builtin_amdgcn_s_setprio(0);
    phase_bar();
    // ---- P1: MFMA(t1 x b0) overlapped with reads of c1, b1; drain all reads
    if (tau + 1 < NT) stageB(tau + 1, 1);
    phase_bar();
    __builtin_amdgcn_s_setprio(1);
    #pragma unroll
    for (int m = 0; m < 4; ++m) c1[m] = ldA(tau, 4 + m, 1);
    #pragma unroll
    for (int n = 0; n < 4; ++n) b1[n] = ldB(tau, n, 1);
    #pragma unroll
    for (int m = 0; m < 4; ++m)
      #pragma unroll
      for (int n = 0; n < 4; ++n)
        acc[4 + m][n] = __builtin_amdgcn_mfma_f32_16x16x32_bf16(t1[m], b0[n], acc[4 + m][n], 0, 0, 0);
    __builtin_amdgcn_s_setprio(0);
    asm volatile("s_waitcnt lgkmcnt(0)" ::: "memory");   // all tau-frag reads drained before A overwrite
    phase_bar();
    // ---- P2: MFMA(c0 x b1), stageA(tau+2,0)
    if (tau + 2 < NT) stageA(tau + 2, 0);
    phase_bar();
    __builtin_amdgcn_s_setprio(1);
    #pragma unroll
    for (int m = 0; m < 4; ++m)
      #pragma unroll
      for (int n = 0; n < 4; ++n)
        acc[m][n] = __builtin_amdgcn_mfma_f32_16x16x32_bf16(c0[m], b1[n], acc[m][n], 0, 0, 0);
    __builtin_amdgcn_s_setprio(0);
    phase_bar();
    // ---- P3: MFMA(c1 x b1) overlapped with next-tile t0, b0 reads
    if (tau + 2 < NT) stageA(tau + 2, 1);
    if (tau < NT - 2) { asm volatile("s_waitcnt vmcnt(4)" ::: "memory"); }
    else              { asm volatile("s_waitcnt vmcnt(0)" ::: "memory"); }
    phase_bar();
    __builtin_amdgcn_s_setprio(1);
    if (tau + 1 < NT) {
      #pragma unroll
      for (int m = 0; m < 4; ++m) t0[m] = ldA(tau + 1, m, 0);
      #pragma unroll
      for (int n = 0; n < 4; ++n) b0[n] = ldB(tau + 1, n, 0);
    }
    #pragma unroll
    for (int m = 0; m < 4; ++m)
      #pragma unroll
      for (int n = 0; n < 4; ++n)
        acc[4 + m][n] = __builtin_amdgcn_mfma_f32_16x16x32_bf16(c1[m], b1[n], acc[4 + m][n], 0, 0, 0);
    __builtin_amdgcn_s_setprio(0);
    phase_bar();
  }

  // epilogue: row-outer store order (4 adjacent 32B bursts per row)
  float bvv[4];
  #pragma unroll
  for (int n = 0; n < 4; ++n) bvv[n] = binj[n0 + wn * 64 + n * 16 + l15];
  #pragma unroll
  for (int m = 0; m < 8; ++m) {
    #pragma unroll
    for (int r = 0; r < 4; ++r) {
      const int grow = r0 + wm * 128 + m * 16 + l4 * 4 + r;
      #pragma unroll
      for (int n = 0; n < 4; ++n) {
        const int gcol = n0 + wn * 64 + n * 16 + l15;
        hout[(size_t)grow * 1024 + gcol] = f2bf(acc[m][n][r] + bvv[n]);
      }
    }
  }
}

// ---------------- GEMM template (m97-style 128x128, BK=32, 4 waves) --------
template<int KTOT, int NTOT, int CTILES, int EPI, int AMODE>
__global__ __launch_bounds__(256, 3) void gemm_k(
    const unsigned short* __restrict__ A,
    const unsigned short* __restrict__ Bm,
    const float* __restrict__ xsrc,
    const float* __restrict__ evec,
    const unsigned short* __restrict__ hbuf,
    void* __restrict__ Cout) {
  const int tid = threadIdx.x;
  const int wv = tid >> 6, ln = tid & 63;
  const int l15 = ln & 15, l4 = ln >> 4;
  const int wr = wv >> 1, wc = wv & 1;
  const int bid = blockIdx.x;
  const int rt = bid / CTILES, ct = bid % CTILES;
  const int r0 = rt << 7, n0 = ct << 7;

  __shared__ unsigned short ldsA[128 * 32];
  __shared__ unsigned short ldsB[128 * 32];

  f32x4 acc[4][4];
  #pragma unroll
  for (int i = 0; i < 4; ++i)
    #pragma unroll
    for (int j = 0; j < 4; ++j)
      acc[i][j] = (f32x4){0.f, 0.f, 0.f, 0.f};

  for (int k0 = 0; k0 < KTOT; k0 += 32) {
    __syncthreads();
    {
      const unsigned short* bb = Bm + (size_t)n0 * KTOT + k0;
      #pragma unroll
      for (int s0 = 0; s0 < 2; ++s0) {
        const int s = wv + s0 * 4;
        const int bo = (s << 10) + (ln << 4);
        const int row = bo >> 6, inb = bo & 63;
        gload16((const char*)(bb + (size_t)row * KTOT) + inb, (char*)ldsB + (s << 10));
      }
    }
    if (AMODE == 1 && k0 >= 2048) {
      const int row = tid >> 1, kf = (tid & 1) << 4;
      const float* xp = xsrc + (size_t)(r0 + row) * 1024 + (k0 - 2048) + kf;
      const float4 v0 = *(const float4*)(xp + 0);
      const float4 v1 = *(const float4*)(xp + 4);
      const float4 v2 = *(const float4*)(xp + 8);
      const float4 v3 = *(const float4*)(xp + 12);
      u16x8 w0, w1;
      w0[0] = f2bf(v0.x); w0[1] = f2bf(v0.y); w0[2] = f2bf(v0.z); w0[3] = f2bf(v0.w);
      w0[4] = f2bf(v1.x); w0[5] = f2bf(v1.y); w0[6] = f2bf(v1.z); w0[7] = f2bf(v1.w);
      w1[0] = f2bf(v2.x); w1[1] = f2bf(v2.y); w1[2] = f2bf(v2.z); w1[3] = f2bf(v2.w);
      w1[4] = f2bf(v3.x); w1[5] = f2bf(v3.y); w1[6] = f2bf(v3.z); w1[7] = f2bf(v3.w);
      *(u16x8*)&ldsA[row * 32 + kf] = w0;
      *(u16x8*)&ldsA[row * 32 + kf + 8] = w1;
    } else {
      const unsigned short* aa;
      int astr;
      if (AMODE == 0) { aa = A + (size_t)r0 * KTOT + k0; astr = KTOT; }
      else { aa = A + (size_t)(k0 >> 10) * (32768u * 1024u) + (size_t)r0 * 1024 + (k0 & 1023); astr = 1024; }
      #pragma unroll
      for (int s0 = 0; s0 < 2; ++s0) {
        const int s = wv + s0 * 4;
        const int bo = (s << 10) + (ln << 4);
        const int row = bo >> 6, inb = bo & 63;
        gload16((const char*)(aa + (size_t)row * astr) + inb, (char*)ldsA + (s << 10));
      }
    }
    __syncthreads();
    bf16x8 af[4], bfr[4];
    #pragma unroll
    for (int i = 0; i < 4; ++i)
      af[i] = *(const bf16x8*)&ldsA[(wr * 64 + i * 16 + l15) * 32 + l4 * 8];
    #pragma unroll
    for (int j = 0; j < 4; ++j)
      bfr[j] = *(const bf16x8*)&ldsB[(wc * 64 + j * 16 + l15) * 32 + l4 * 8];
    #pragma unroll
    for (int i = 0; i < 4; ++i)
      #pragma unroll
      for (int j = 0; j < 4; ++j)
        acc[i][j] = __builtin_amdgcn_mfma_f32_16x16x32_bf16(af[i], bfr[j], acc[i][j], 0, 0, 0);
  }

  // epilogue: row-outer store order
  float ev[4];
  #pragma unroll
  for (int j = 0; j < 4; ++j)
    ev[j] = (EPI == 1 || EPI == 3) ? evec[n0 + wc * 64 + j * 16 + l15] : 0.f;
  #pragma unroll
  for (int i = 0; i < 4; ++i) {
    #pragma unroll
    for (int r = 0; r < 4; ++r) {
      const int gr = r0 + wr * 64 + i * 16 + l4 * 4 + r;
      #pragma unroll
      for (int j = 0; j < 4; ++j) {
        const int gcol = n0 + wc * 64 + j * 16 + l15;
        const size_t idx = (size_t)gr * NTOT + gcol;
        const float v = acc[i][j][r];
        if (EPI == 1)      ((unsigned short*)Cout)[idx] = f2bf(v + ev[j]);
        else if (EPI == 2) ((float*)Cout)[idx] = v;
        else               ((float*)Cout)[idx] = v + ev[j] * bf2f(hbuf[idx]);
      }
    }
  }
}

// ---------------- FAST: fused Bu GEMM + chunk-aggregate scans + w2 ----------
// Round-8: double-buffered K-loop with vmcnt(4) (no full drains).
__global__ __launch_bounds__(256) void gemm_bu_k(
    const unsigned short* __restrict__ A, const unsigned short* __restrict__ Bm,
    float* __restrict__ Bu, float* __restrict__ agg,
    const float* __restrict__ Lre, const float* __restrict__ Lim,
    const float* __restrict__ logdt,
    const float* __restrict__ Cfre, const float* __restrict__ Cfim,
    const float* __restrict__ Cbre, const float* __restrict__ Cbim,
    unsigned short* __restrict__ W2T) {
  const int tid = threadIdx.x;
  if (blockIdx.x >= 256) {
    const int idx = (blockIdx.x - 256) * 256 + tid;
    const int h = idx >> 8, k = idx & 255;
    const int p = (k & 127) >> 1, im = k & 1, bw = k >> 7;
    const float* Cre = bw ? Cbre : Cfre;
    const float* Cim = bw ? Cbim : Cfim;
    const float v = im ? (-2.f * Cim[h * 64 + p]) : (2.f * Cre[h * 64 + p]);
    W2T[idx] = f2bf(v);
    return;
  }
  __shared__ unsigned short ldsA[2][128 * 32];
  __shared__ unsigned short ldsB[2][128 * 32];
  __shared__ float cbuf[128][128];
  const int wv = tid >> 6, ln = tid & 63;
  const int l15 = ln & 15, l4 = ln >> 4;
  const int wr = wv >> 1, wc = wv & 1;
  const int r0 = blockIdx.x << 7;

  auto stg = [&](int k) {      // 4 gloads/thread into parity k&1
    const int par = k & 1;
    const unsigned short* bb = Bm + k * 32;
    const unsigned short* aa = A + (size_t)r0 * 1024 + k * 32;
    #pragma unroll
    for (int s0 = 0; s0 < 2; ++s0) {
      const int s = wv + s0 * 4;
      const int bo = (s << 10) + (ln << 4);
      const int row = bo >> 6, inb = bo & 63;
      gload16((const char*)(bb + (size_t)row * 1024) + inb, (char*)ldsB[par] + (s << 10));
    }
    #pragma unroll
    for (int s0 = 0; s0 < 2; ++s0) {
      const int s = wv + s0 * 4;
      const int bo = (s << 10) + (ln << 4);
      const int row = bo >> 6, inb = bo & 63;
      gload16((const char*)(aa + (size_t)row * 1024) + inb, (char*)ldsA[par] + (s << 10));
    }
  };

  f32x4 acc[4][4];
  #pragma unroll
  for (int i = 0; i < 4; ++i)
    #pragma unroll
    for (int j = 0; j < 4; ++j)
      acc[i][j] = (f32x4){0.f, 0.f, 0.f, 0.f};

  stg(0);
  for (int k = 0; k < 32; ++k) {
    const int par = k & 1;
    if (k + 1 < 32) { stg(k + 1); asm volatile("s_waitcnt vmcnt(4)" ::: "memory"); }
    else            { asm volatile("s_waitcnt vmcnt(0)" ::: "memory"); }
    __builtin_amdgcn_s_barrier();
    bf16x8 af[4], bfr[4];
    #pragma unroll
    for (int i = 0; i < 4; ++i)
      af[i] = *(const bf16x8*)&ldsA[par][(wr * 64 + i * 16 + l15) * 32 + l4 * 8];
    #pragma unroll
    for (int j = 0; j < 4; ++j)
      bfr[j] = *(const bf16x8*)&ldsB[par][(wc * 64 + j * 16 + l15) * 32 + l4 * 8];
    #pragma unroll
    for (int i = 0; i < 4; ++i)
      #pragma unroll
      for (int j = 0; j < 4; ++j)
        acc[i][j] = __builtin_amdgcn_mfma_f32_16x16x32_bf16(af[i], bfr[j], acc[i][j], 0, 0, 0);
    __builtin_amdgcn_s_barrier();   // reads of parity done before stg(k+2) overwrites
  }

  // epilogue: write C to global Bu (row-burst order) AND LDS cbuf
  #pragma unroll
  for (int i = 0; i < 4; ++i) {
    #pragma unroll
    for (int r = 0; r < 4; ++r) {
      const int lr = wr * 64 + i * 16 + l4 * 4 + r;
      #pragma unroll
      for (int j = 0; j < 4; ++j) {
        const int lcol = wc * 64 + j * 16 + l15;
        const float v = acc[i][j][r];
        Bu[(size_t)(r0 + lr) * 128 + lcol] = v;
        cbuf[lr][lcol] = v;
      }
    }
  }
  __syncthreads();
  // waves 0/1: fwd/bwd chunk-aggregate scans (64 lanes = p)
  if (wv < 2) {
    const int dir = wv, p = ln;
    const float dt = expf(logdt[p]);
    const float e = expf(Lre[p] * dt);
    float sn, cs; sincosf(Lim[p] * dt, &sn, &cs);
    const float ar = e * cs, ai = e * sn;
    float sr = 0.f, si = 0.f;
    for (int i = 0; i < 128; ++i) {
      const int off = dir ? (127 - i) : i;
      const float vr = cbuf[off][2 * p];
      const float vi = cbuf[off][2 * p + 1];
      const float nr = ar * sr - ai * si + vr;
      const float ni = ar * si + ai * sr + vi;
      sr = nr; si = ni;
    }
    const int b = r0 >> 13, ch = (r0 & 8191) >> 7;
    float* o = agg + (((size_t)dir * 4 + b) * 64 + ch) * 128 + 2 * p;
    o[0] = sr; o[1] = si;
  }
}

// ---------------- K5 (fallback): per-chunk scan aggregates ------------------
__global__ void scan_agg_k(const float* __restrict__ Bu, float* __restrict__ agg,
                           const float* __restrict__ Lre, const float* __restrict__ Lim,
                           const float* __restrict__ logdt) {
  const int bid = blockIdx.x;
  const int dir = bid >> 8, b = (bid >> 6) & 3, ch = bid & 63;
  const int p = threadIdx.x;
  const float dt = expf(logdt[p]);
  const float e = expf(Lre[p] * dt);
  float sn, cs; sincosf(Lim[p] * dt, &sn, &cs);
  const float ar = e * cs, ai = e * sn;
  const int l0 = ch << 7;
  const float* base = Bu + ((size_t)b * 8192 + l0) * 128 + 2 * p;
  float sr = 0.f, si = 0.f;
  for (int g = 0; g < 16; ++g) {
    float2 v[8];
    #pragma unroll
    for (int u = 0; u < 8; ++u) {
      const int i = g * 8 + u;
      const int off = dir ? (127 - i) : i;
      v[u] = *(const float2*)(base + (size_t)off * 128);
    }
    #pragma unroll
    for (int u = 0; u < 8; ++u) {
      const float nr = ar * sr - ai * si + v[u].x;
      const float ni = ar * si + ai * sr + v[u].y;
      sr = nr; si = ni;
    }
  }
  float* o = agg + (((size_t)dir * 4 + b) * 64 + ch) * 128 + 2 * p;
  o[0] = sr; o[1] = si;
}

// ---------------- K6: combine chunk aggregates ------------------------------
__global__ void scan_comb_k(const float* __restrict__ agg, float* __restrict__ pre,
                            const float* __restrict__ Lre, const float* __restrict__ Lim,
                            const float* __restrict__ logdt) {
  const int dir = blockIdx.x >> 2, b = blockIdx.x & 3;
  const int p = threadIdx.x;
  const float dt = expf(logdt[p]);
  const float e = expf(Lre[p] * dt);
  float sn, cs; sincosf(Lim[p] * dt, &sn, &cs);
  float Ar = e * cs, Ai = e * sn;
  #pragma unroll
  for (int q = 0; q < 7; ++q) {
    const float nr = Ar * Ar - Ai * Ai; Ai = 2.f * Ar * Ai; Ar = nr;
  }
  const float* ab = agg + ((size_t)(dir * 4 + b) * 64) * 128 + 2 * p;
  float* pb = pre + ((size_t)(dir * 4 + b) * 64) * 128 + 2 * p;
  float sr = 0.f, si = 0.f;
  for (int g = 0; g < 8; ++g) {
    float2 v[8];
    #pragma unroll
    for (int u = 0; u < 8; ++u) {
      const int i = g * 8 + u;
      const int ch = dir ? (63 - i) : i;
      v[u] = *(const float2*)(ab + (size_t)ch * 128);
    }
    #pragma unroll
    for (int u = 0; u < 8; ++u) {
      const int i = g * 8 + u;
      const int ch = dir ? (63 - i) : i;
      pb[(size_t)ch * 128] = sr; pb[(size_t)ch * 128 + 1] = si;
      const float nr = Ar * sr - Ai * si + v[u].x;
      const float ni = Ar * si + Ai * sr + v[u].y;
      sr = nr; si = ni;
    }
  }
}

// ---------------- K7: apply with precomputed prefix -------------------------
__global__ void scan_apply_k(const float* __restrict__ Bu, const float* __restrict__ pre,
                             unsigned short* __restrict__ Xcat,
                             const float* __restrict__ Lre, const float* __restrict__ Lim,
                             const float* __restrict__ logdt) {
  const int bid = blockIdx.x;
  const int dir = bid >> 8, b = (bid >> 6) & 3, ch = bid & 63;
  const int p = threadIdx.x;
  const float dt = expf(logdt[p]);
  const float e = expf(Lre[p] * dt);
  float sn, cs; sincosf(Lim[p] * dt, &sn, &cs);
  const float ar = e * cs, ai = e * sn;
  const int l0 = ch << 7;
  const float* base = Bu + ((size_t)b * 8192 + l0) * 128 + 2 * p;
  const float* pr = pre + (((size_t)dir * 4 + b) * 64 + ch) * 128 + 2 * p;
  float sr = pr[0], si = pr[1];
  unsigned short* xb = Xcat + ((size_t)b * 8192 + l0) * 256 + dir * 128 + 2 * p;
  for (int g = 0; g < 16; ++g) {
    float2 v[8];
    #pragma unroll
    for (int u = 0; u < 8; ++u) {
      const int i = g * 8 + u;
      const int off = dir ? (127 - i) : i;
      v[u] = *(const float2*)(base + (size_t)off * 128);
    }
    #pragma unroll
    for (int u = 0; u < 8; ++u) {
      const int i = g * 8 + u;
      const int off = dir ? (127 - i) : i;
      const float nr = ar * sr - ai * si + v[u].x;
      const float ni = ar * si + ai * sr + v[u].y;
      sr = nr; si = ni;
      ushort2 ov; ov.x = f2bf(sr); ov.y = f2bf(si);
      *(ushort2*)(xb + (size_t)off * 256) = ov;
    }
  }
}

// ---------------------------------------------------------------------------
extern "C" void kernel_launch(void* const* d_in, const int* in_sizes, int n_in,
                              void* d_out, int out_size, void* d_ws, size_t ws_size,
                              hipStream_t stream) {
  const float* zH    = (const float*)d_in[0];
  const float* zL    = (const float*)d_in[1];
  const float* x     = (const float*)d_in[2];
  const float* t     = (const float*)d_in[3];
  const float* WpH   = (const float*)d_in[4];
  const float* bpH   = (const float*)d_in[5];
  const float* WpL   = (const float*)d_in[6];
  const float* bpL   = (const float*)d_in[7];
  const float* Winj  = (const float*)d_in[8];
  const float* binj  = (const float*)d_in[9];
  const float* Lre   = (const float*)d_in[10];
  const float* Lim   = (const float*)d_in[11];
  const float* Bre   = (const float*)d_in[12];
  const float* Bim   = (const float*)d_in[13];
  const float* Cfre  = (const float*)d_in[14];
  const float* Cfim  = (const float*)d_in[15];
  const float* Cbre  = (const float*)d_in[16];
  const float* Cbim  = (const float*)d_in[17];
  const float* Dv    = (const float*)d_in[18];
  const float* logdt = (const float*)d_in[19];

  unsigned short* znH = (unsigned short*)d_out;          // d_out as scratch until K8
  unsigned short* znL = znH + (size_t)32768 * 1024;

  const bool FAST = ws_size >= 141950976ull;
  char* ws = (char*)d_ws;

  if (FAST) {
    unsigned short* WinjT = (unsigned short*)(ws + 0);
    unsigned short* hbuf  = (unsigned short*)(ws + 6291456);
    unsigned short* WBuT  = (unsigned short*)(ws + 73400320);
    float*          cond  = (float*)(ws + 73662464);
    float*          part  = (float*)(ws + 73793536);
    char*           U     = ws + 74842112;               // union region
    unsigned short* xbf   = (unsigned short*)U;          // 64 MB, dead after inj GEMM
    float*          Bu    = (float*)(U + 0);             // 16 MB (after gemm8p)
    float*          agg   = (float*)(U + 16777216);      // 256 KB
    float*          pre   = (float*)(U + 17039360);      // 256 KB
    unsigned short* Xcat  = (unsigned short*)(U + 17301504);  // 16 MB
    unsigned short* W2T   = (unsigned short*)(U + 34078720);  // 0.5 MB (after gemm8p)

    prep_k<<<1536, 256, 0, stream>>>(Winj, WinjT, Lre, Lim, logdt, Bre, Bim, WBuT,
                                     t, WpH, WpL, part);
    proj_red_k<<<64, 256, 0, stream>>>(part, bpH, bpL, cond);
    adaln_k<<<32768, 256, 0, stream>>>(zH, zL, x, cond, znH, znL, xbf);
    gemm8p_k<<<512, 512, 0, stream>>>(znH, znL, xbf, WinjT, binj, hbuf);
    gemm_bu_k<<<1280, 256, 0, stream>>>(hbuf, WBuT, Bu, agg, Lre, Lim, logdt,
                                        Cfre, Cfim, Cbre, Cbim, W2T);
    scan_comb_k<<<8, 64, 0, stream>>>(agg, pre, Lre, Lim, logdt);
    scan_apply_k<<<512, 64, 0, stream>>>(Bu, pre, Xcat, Lre, Lim, logdt);
    gemm_k<256, 1024, 8, 3, 0><<<2048, 256, 0, stream>>>(Xcat, W2T, nullptr, Dv, hbuf, (float*)d_out);
  } else {
    // round-1 fallback (ws >= 108.4 MB proven)
    unsigned short* WinjT = (unsigned short*)ws; ws += (size_t)1024 * 3072 * 2;
    unsigned short* hbuf  = (unsigned short*)ws; ws += (size_t)32768 * 1024 * 2;
    unsigned short* WBuT  = (unsigned short*)ws; ws += (size_t)128 * 1024 * 2;
    float*          Bu    = (float*)ws;          ws += (size_t)32768 * 128 * 4;
    float*          cond  = (float*)ws;          ws += (size_t)2 * 2 * 4 * 1024 * 4;
    float*          agg   = (float*)ws;          ws += (size_t)2 * 4 * 64 * 128 * 4;
    float*          pre   = (float*)ws;          ws += (size_t)2 * 4 * 64 * 128 * 4;
    unsigned short* Xcat  = (unsigned short*)ws; ws += (size_t)32768 * 256 * 2;
    unsigned short* W2T   = (unsigned short*)ws; ws += (size_t)1024 * 256 * 2;

    proj_k<<<16, 256, 0, stream>>>(t, WpH, bpH, WpL, bpL, cond);
    transpose_winj<<<768, 256, 0, stream>>>(Winj, WinjT);
    wbu_k<<<512, 256, 0, stream>>>(Lre, Lim, logdt, Bre, Bim, WBuT);
    w2_k<<<1024, 256, 0, stream>>>(Cfre, Cfim, Cbre, Cbim, W2T);
    adaln_k<<<32768, 256, 0, stream>>>(zH, zL, x, cond, znH, znL, nullptr);
    gemm_k<3072, 1024, 8, 1, 1><<<2048, 256, 0, stream>>>(znH, WinjT, x, binj, nullptr, hbuf);
    gemm_k<1024, 128, 1, 2, 0><<<256, 256, 0, stream>>>(hbuf, WBuT, nullptr, nullptr, nullptr, Bu);
    scan_agg_k<<<512, 64, 0, stream>>>(Bu, agg, Lre, Lim, logdt);
    scan_comb_k<<<8, 64, 0, stream>>>(agg, pre, Lre, Lim, logdt);
    scan_apply_k<<<512, 64, 0, stream>>>(Bu, pre, Xcat, Lre, Lim, logdt);
    gemm_k<256, 1024, 8, 3, 0><<<2048, 256, 0, stream>>>(Xcat, W2T, nullptr, Dv, hbuf, (float*)d_out);
  }
}